// Round 7
// baseline (416.368 us; speedup 1.0000x reference)
//
#include <hip/hip_runtime.h>
#include <math.h>

#define B_DIM 512
#define K_DIM 2048
#define N_DIM 4096
#define BRN 16
#define NUM_TARGET 4096

#define THR_MIN 0.5
#define THR_MAX 2.0
#define REFRACT 2.0f
#define LN_EPS 1e-5

#if defined(__has_builtin)
#if __has_builtin(__builtin_amdgcn_mfma_f64_16x16x4f64)
#define HAVE_MFMA64 1
#endif
#endif
#ifndef HAVE_MFMA64
#define HAVE_MFMA64 0
#endif

typedef __attribute__((ext_vector_type(4))) double d4_t;

// ================= GEMM (f64 exact): dend = X[B,K] @ W[N,K]^T + b ==========
#define BM 64
#define BN 64

#if HAVE_MFMA64
// MFMA f64 path: 64x64 tile, BK=32, 256 thr (4 waves, each 32x32 out).
#define BKK 32
#define LDK 34   // f64 row stride: even (16B-aligned b128) + bank-spread

__global__ __launch_bounds__(256) void gemm_mfma64_kernel(
    const float* __restrict__ X,    // [B, K]
    const float* __restrict__ W,    // [N, K]
    const float* __restrict__ bias, // [N]
    float* __restrict__ dhi,        // [B, N]
    float* __restrict__ dlo)        // [B, N]
{
    __shared__ double As[BM][LDK];  // [batch-row][k]
    __shared__ double Bs[BN][LDK];  // [neuron-col][k]

    const int t    = threadIdx.x;
    const int lane = t & 63;
    const int wv   = t >> 6;
    const int wr   = (wv >> 1) * 32;   // wave's row quadrant
    const int wc   = (wv & 1) * 32;    // wave's col quadrant
    const int l15  = lane & 15;
    const int lg   = lane >> 4;

    const int row0 = blockIdx.x * BM;
    const int col0 = blockIdx.y * BN;

    // staging map: thread t loads float4 at (row sr, k sk) and (sr+32, sk)
    const int sr = t >> 3;          // 0..31
    const int sk = (t & 7) * 4;     // 0,4,...,28
    const float* xp0 = &X[(size_t)(row0 + sr) * K_DIM + sk];
    const float* xp1 = xp0 + (size_t)32 * K_DIM;
    const float* wp0 = &W[(size_t)(col0 + sr) * K_DIM + sk];
    const float* wp1 = wp0 + (size_t)32 * K_DIM;

    d4_t acc00 = {0.,0.,0.,0.}, acc01 = {0.,0.,0.,0.};
    d4_t acc10 = {0.,0.,0.,0.}, acc11 = {0.,0.,0.,0.};

    // prefetch k0 = 0
    float4 xa0 = *(const float4*)(xp0);
    float4 xa1 = *(const float4*)(xp1);
    float4 wb0 = *(const float4*)(wp0);
    float4 wb1 = *(const float4*)(wp1);

    for (int k0 = 0; k0 < K_DIM; k0 += BKK) {
        __syncthreads();   // previous compute done, LDS reusable
        As[sr     ][sk+0] = (double)xa0.x; As[sr     ][sk+1] = (double)xa0.y;
        As[sr     ][sk+2] = (double)xa0.z; As[sr     ][sk+3] = (double)xa0.w;
        As[sr + 32][sk+0] = (double)xa1.x; As[sr + 32][sk+1] = (double)xa1.y;
        As[sr + 32][sk+2] = (double)xa1.z; As[sr + 32][sk+3] = (double)xa1.w;
        Bs[sr     ][sk+0] = (double)wb0.x; Bs[sr     ][sk+1] = (double)wb0.y;
        Bs[sr     ][sk+2] = (double)wb0.z; Bs[sr     ][sk+3] = (double)wb0.w;
        Bs[sr + 32][sk+0] = (double)wb1.x; Bs[sr + 32][sk+1] = (double)wb1.y;
        Bs[sr + 32][sk+2] = (double)wb1.z; Bs[sr + 32][sk+3] = (double)wb1.w;
        __syncthreads();

        if (k0 + BKK < K_DIM) {        // prefetch next tile; hides under MFMA
            xa0 = *(const float4*)(xp0 + k0 + BKK);
            xa1 = *(const float4*)(xp1 + k0 + BKK);
            wb0 = *(const float4*)(wp0 + k0 + BKK);
            wb1 = *(const float4*)(wp1 + k0 + BKK);
        }

        #pragma unroll
        for (int kk = 0; kk < BKK; kk += 4) {
            // A-frag: lane holds A[l15][lg]; B-frag: B[lg][l15]
            double a0 = As[wr      + l15][kk + lg];
            double a1 = As[wr + 16 + l15][kk + lg];
            double b0 = Bs[wc      + l15][kk + lg];
            double b1 = Bs[wc + 16 + l15][kk + lg];
            acc00 = __builtin_amdgcn_mfma_f64_16x16x4f64(a0, b0, acc00, 0, 0, 0);
            acc01 = __builtin_amdgcn_mfma_f64_16x16x4f64(a0, b1, acc01, 0, 0, 0);
            acc10 = __builtin_amdgcn_mfma_f64_16x16x4f64(a1, b0, acc10, 0, 0, 0);
            acc11 = __builtin_amdgcn_mfma_f64_16x16x4f64(a1, b1, acc11, 0, 0, 0);
        }
    }

    // epilogue: D[row=(lg*4+q), col=l15] per 16x16 tile
    #pragma unroll
    for (int i = 0; i < 2; ++i) {
        #pragma unroll
        for (int j = 0; j < 2; ++j) {
            d4_t a = (i == 0) ? (j == 0 ? acc00 : acc01)
                              : (j == 0 ? acc10 : acc11);
            const int cl = col0 + wc + j * 16 + l15;
            const double bd = (double)bias[cl];
            #pragma unroll
            for (int q = 0; q < 4; ++q) {
                const int rl = row0 + wr + i * 16 + lg * 4 + q;
                double v = a[q] + bd;
                float hv = (float)v;
                float lv = (float)(v - (double)hv);
                dhi[(size_t)rl * N_DIM + cl] = hv;
                dlo[(size_t)rl * N_DIM + cl] = lv;
            }
        }
    }
}
#endif  // HAVE_MFMA64

// VALU f64 fallback (proven correct, Round 6)
#define BK 32
#define LPAD 68
__global__ __launch_bounds__(256) void gemm_f64acc_kernel(
    const float* __restrict__ X, const float* __restrict__ W,
    const float* __restrict__ bias, float* __restrict__ dhi, float* __restrict__ dlo)
{
    __shared__ float As[BK][LPAD];
    __shared__ float Bs[BK][LPAD];
    const int t = threadIdx.x;
    const int row0 = blockIdx.x * BM;
    const int col0 = blockIdx.y * BN;
    const int tn = t & 15;
    const int tm = t >> 4;
    double acc[4][4] = {{0,0,0,0},{0,0,0,0},{0,0,0,0},{0,0,0,0}};
    for (int k0 = 0; k0 < K_DIM; k0 += BK) {
        #pragma unroll
        for (int i = 0; i < 2; ++i) {
            int lin = t + i * 256;
            int r   = lin >> 3;
            int k4  = lin & 7;
            float4 a = *(const float4*)&X[(row0 + r) * K_DIM + k0 + k4 * 4];
            As[k4*4+0][r] = a.x; As[k4*4+1][r] = a.y;
            As[k4*4+2][r] = a.z; As[k4*4+3][r] = a.w;
            float4 w = *(const float4*)&W[(col0 + r) * K_DIM + k0 + k4 * 4];
            Bs[k4*4+0][r] = w.x; Bs[k4*4+1][r] = w.y;
            Bs[k4*4+2][r] = w.z; Bs[k4*4+3][r] = w.w;
        }
        __syncthreads();
        #pragma unroll
        for (int k = 0; k < BK; ++k) {
            float4 a = *(const float4*)&As[k][tm * 4];
            float4 b = *(const float4*)&Bs[k][tn * 4];
            double ax=a.x, ay=a.y, az=a.z, aw=a.w;
            double bx=b.x, by=b.y, bz=b.z, bw=b.w;
            acc[0][0]+=ax*bx; acc[0][1]+=ax*by; acc[0][2]+=ax*bz; acc[0][3]+=ax*bw;
            acc[1][0]+=ay*bx; acc[1][1]+=ay*by; acc[1][2]+=ay*bz; acc[1][3]+=ay*bw;
            acc[2][0]+=az*bx; acc[2][1]+=az*by; acc[2][2]+=az*bz; acc[2][3]+=az*bw;
            acc[3][0]+=aw*bx; acc[3][1]+=aw*by; acc[3][2]+=aw*bz; acc[3][3]+=aw*bw;
        }
        __syncthreads();
    }
    float4 bv = *(const float4*)&bias[col0 + tn * 4];
    double bvd[4] = {(double)bv.x,(double)bv.y,(double)bv.z,(double)bv.w};
    #pragma unroll
    for (int i = 0; i < 4; ++i) {
        int row = row0 + tm * 4 + i;
        #pragma unroll
        for (int q = 0; q < 4; ++q) {
            double v = acc[i][q] + bvd[q];
            float hv = (float)v;
            float lv = (float)(v - (double)hv);
            dhi[row * N_DIM + col0 + tn * 4 + q] = hv;
            dlo[row * N_DIM + col0 + tn * 4 + q] = lv;
        }
    }
}

// ================= factors precompute: fac = clip(att)*0.9^delay ============
__device__ inline float pow09(int d) {
    switch (d) {
        case 0: return 1.0f;
        case 1: return 0.9f;
        case 2: return 0.81f;
        case 3: return 0.729f;
        case 4: return 0.6561f;
        case 5: return 0.59049f;
        default: return powf(0.9f, (float)d);
    }
}

__global__ __launch_bounds__(256) void factors_kernel(
    const float* __restrict__ att, const int* __restrict__ dly,
    float* __restrict__ fac)
{
    int i = blockIdx.x * 256 + threadIdx.x;    // N_DIM*BRN total
    float a = fminf(fmaxf(att[i], 0.f), 1.f);
    fac[i] = a * pow09(dly[i]);
}

// ======== fused LayerNorm + soma + axon scatter, one block per row ==========
template <int USE_FAC>
__global__ __launch_bounds__(512) void fused_row_kernel(
    const float* __restrict__ dhi, const float* __restrict__ dlo,
    const float* __restrict__ mem_i, const float* __restrict__ ref_i,
    const float* __restrict__ gamma, const float* __restrict__ beta,
    const float* __restrict__ thr_p, const float* __restrict__ dec_p,
    const float* __restrict__ att, const int* __restrict__ tgt,
    const int* __restrict__ dly, const float* __restrict__ fac,
    float* __restrict__ axon_o, float* __restrict__ spike_o,
    float* __restrict__ mem_o, float* __restrict__ ref_o)
{
    __shared__ double sm_d[N_DIM];          // 32 KB
    __shared__ float  sm_axon[NUM_TARGET];  // 16 KB
    __shared__ double red[8];

    const int b = blockIdx.x;
    const int t = threadIdx.x;
    const int lane = t & 63;
    const int wv = t >> 6;
    const float* hrow = dhi + (size_t)b * N_DIM;
    const float* lrow = dlo + (size_t)b * N_DIM;

    for (int i = t; i < NUM_TARGET; i += 512) sm_axon[i] = 0.f;

    double s = 0.0;
    #pragma unroll
    for (int j = 0; j < 2; ++j) {
        int i = t + j * 512;                 // float4 index (1024 total)
        float4 h = ((const float4*)hrow)[i];
        float4 l = ((const float4*)lrow)[i];
        double d0 = (double)h.x + (double)l.x;
        double d1 = (double)h.y + (double)l.y;
        double d2 = (double)h.z + (double)l.z;
        double d3 = (double)h.w + (double)l.w;
        sm_d[i*4+0] = d0; sm_d[i*4+1] = d1;
        sm_d[i*4+2] = d2; sm_d[i*4+3] = d3;
        s += d0 + d1 + d2 + d3;
    }
    #pragma unroll
    for (int o = 32; o > 0; o >>= 1) s += __shfl_down(s, o, 64);
    if (lane == 0) red[wv] = s;
    __syncthreads();
    const double mu = (red[0]+red[1]+red[2]+red[3]+red[4]+red[5]+red[6]+red[7])
                      * (1.0 / 4096.0);

    double vs = 0.0;
    #pragma unroll
    for (int j = 0; j < 2; ++j) {
        int i = t + j * 512;
        double d0 = sm_d[i*4+0]-mu, d1 = sm_d[i*4+1]-mu;
        double d2 = sm_d[i*4+2]-mu, d3 = sm_d[i*4+3]-mu;
        vs += d0*d0 + d1*d1 + d2*d2 + d3*d3;
    }
    #pragma unroll
    for (int o = 32; o > 0; o >>= 1) vs += __shfl_down(vs, o, 64);
    __syncthreads();                        // mu reads of red[] done
    if (lane == 0) red[wv] = vs;
    __syncthreads();
    const double var = (red[0]+red[1]+red[2]+red[3]+red[4]+red[5]+red[6]+red[7])
                       * (1.0 / 4096.0);
    const double rstd = 1.0 / sqrt(var + LN_EPS);

    for (int n = t; n < N_DIM; n += 512) {
        const int gi = b * N_DIM + n;
        double dv = (sm_d[n] - mu) * rstd * (double)gamma[n] + (double)beta[n];
        double d  = fmin(fmax((double)dec_p[n], 0.0), 1.0);
        double th = fmin(fmax((double)thr_p[n], THR_MIN), THR_MAX);
        float  rf = ref_i[gi];
        double nm = d * (double)mem_i[gi] + dv;
        bool   fired = (nm >= th) && (rf <= 0.f);
        float  sp = fired ? 1.f : 0.f;
        if (fired) nm -= th;
        float  nr = fired ? REFRACT : fmaxf(rf - 1.f, 0.f);
        float  nmf = (float)nm;
        spike_o[gi] = sp;
        mem_o[gi]   = nmf;
        ref_o[gi]   = nr;

        float sig = sp + 0.1f * (1.0f / (1.0f + expf(-nmf)));
        const int base = n * BRN;
        #pragma unroll
        for (int j = 0; j < BRN; j += 4) {
            int4 t4 = *(const int4*)&tgt[base + j];
            float f0, f1, f2, f3;
            if (USE_FAC) {
                float4 f4 = *(const float4*)&fac[base + j];
                f0 = f4.x; f1 = f4.y; f2 = f4.z; f3 = f4.w;
            } else {
                float4 a4 = *(const float4*)&att[base + j];
                int4  d4 = *(const int4*)&dly[base + j];
                f0 = fminf(fmaxf(a4.x,0.f),1.f) * pow09(d4.x);
                f1 = fminf(fmaxf(a4.y,0.f),1.f) * pow09(d4.y);
                f2 = fminf(fmaxf(a4.z,0.f),1.f) * pow09(d4.z);
                f3 = fminf(fmaxf(a4.w,0.f),1.f) * pow09(d4.w);
            }
            atomicAdd(&sm_axon[t4.x], sig * f0);
            atomicAdd(&sm_axon[t4.y], sig * f1);
            atomicAdd(&sm_axon[t4.z], sig * f2);
            atomicAdd(&sm_axon[t4.w], sig * f3);
        }
    }
    __syncthreads();

    float* arow = axon_o + (size_t)b * NUM_TARGET;
    for (int i = t; i < NUM_TARGET / 4; i += 512)
        ((float4*)arow)[i] = ((const float4*)sm_axon)[i];
}

extern "C" void kernel_launch(void* const* d_in, const int* in_sizes, int n_in,
                              void* d_out, int out_size, void* d_ws, size_t ws_size,
                              hipStream_t stream) {
    const float* x     = (const float*)d_in[0];
    const float* mem   = (const float*)d_in[1];
    const float* refr  = (const float*)d_in[2];
    const float* W     = (const float*)d_in[3];
    const float* bias  = (const float*)d_in[4];
    const float* gamma = (const float*)d_in[5];
    const float* beta  = (const float*)d_in[6];
    const float* thr   = (const float*)d_in[7];
    const float* dec   = (const float*)d_in[8];
    const float* att   = (const float*)d_in[9];
    const int*   tgt   = (const int*)d_in[10];
    const int*   dly   = (const int*)d_in[11];

    float* out   = (float*)d_out;
    const int SEC = B_DIM * N_DIM;
    float* axon  = out;
    float* spike = out + SEC;
    float* nmem  = out + 2 * SEC;
    float* nref  = out + 3 * SEC;
    float* dhi   = nmem;
    float* dlo   = spike;

    const size_t fac_bytes = (size_t)N_DIM * BRN * sizeof(float);
    const bool use_fac = ws_size >= fac_bytes;
    float* fac = (float*)d_ws;
    if (use_fac)
        factors_kernel<<<(N_DIM * BRN) / 256, 256, 0, stream>>>(att, dly, fac);

    dim3 gg(B_DIM / BM, N_DIM / BN);
#if HAVE_MFMA64
    gemm_mfma64_kernel<<<gg, 256, 0, stream>>>(x, W, bias, dhi, dlo);
#else
    gemm_f64acc_kernel<<<gg, 256, 0, stream>>>(x, W, bias, dhi, dlo);
#endif

    if (use_fac)
        fused_row_kernel<1><<<B_DIM, 512, 0, stream>>>(
            dhi, dlo, mem, refr, gamma, beta, thr, dec, att, tgt, dly, fac,
            axon, spike, nmem, nref);
    else
        fused_row_kernel<0><<<B_DIM, 512, 0, stream>>>(
            dhi, dlo, mem, refr, gamma, beta, thr, dec, att, tgt, dly, nullptr,
            axon, spike, nmem, nref);
}